// Round 10
// baseline (335.051 us; speedup 1.0000x reference)
//
#include <hip/hip_runtime.h>

#define BATCH 32
#define TIME  512
#define INF   512
#define HIDF  1024

#define MBT  256          // block tile: bt rows
#define NBH  128          // block tile: h cols
#define KCH  16           // k per chunk
#define NCH  (INF / KCH)  // 32 chunks
#define XTILEF (MBT * KCH) // 4096 floats = 16 KB per buffer
#define WTILEF (NBH * KCH) // 2048 floats =  8 KB per buffer

// async global->LDS DMA, 16 B per lane, dst = wave-uniform base + lane*16
#define GLD16(g, l) __builtin_amdgcn_global_load_lds(                      \
    (const __attribute__((address_space(1))) void*)(g),                    \
    (__attribute__((address_space(3))) void*)(l), 16, 0, 0)

// ---------------------------------------------------------------------------
// Phase 1: hidden[bt][h] = (sum_k x[bt,k]*W[h,k]) + bias[h], bit-exact vs the
// XLA canonical order (verified R3): ONE fp32 accumulator per output, fused
// FMA, k strictly ascending, ONE fp32 rounding for +bias.
//
// R9 post-mortem: conflicts -> 0 but time flat: the per-CU LDS pipe is the
// wall (~12 cyc per b128 read incl. broadcast writeback; 8.39M reads = 164us
// > 109us FMA floor). Fix: 16x8 thread tile (4RC/(R+C): 16 -> 21.3 FMA/read),
// block 256x128, waves 2x2 of 128x64. LDS reads drop to 6.29M (~123us);
// barrier events halve. Swizzle scheme unchanged (stride-8/16 row offsets
// preserve the quad key; fragment reads stay conflict-free).
// ---------------------------------------------------------------------------
__global__ __launch_bounds__(256, 2)
void snn_gemm_seqfma(const float* __restrict__ x, const float* __restrict__ W,
                     const float* __restrict__ bias, float* __restrict__ hidden) {
    __shared__ __align__(16) float xs[2 * XTILEF];   // 32 KB
    __shared__ __align__(16) float ws[2 * WTILEF];   // 16 KB

    const int tid = threadIdx.x;
    const int l   = tid & 63;
    const int wv  = __builtin_amdgcn_readfirstlane(tid >> 6);  // wave 0..3
    const int lx  = l & 7;           // h lane: cols wh + lx + 8c   (c<8)
    const int ly  = (l >> 3) & 7;    // bt lane: rows wbt + ly + 8r (r<16)
    const int bt0 = blockIdx.y * MBT;
    const int h0  = blockIdx.x * NBH;
    const int wbt = 128 * (wv >> 1); // wave sub-tile origin: bt 0 or 128
    const int wh  = 64 * (wv & 1);   //                        h 0 or 64

    // ---- DMA staging. LDS slot for (row, logical quad q):
    // row*16 + (q ^ ((row>>1)&3))*4. Lane l writes 16 B at float offset 4l ->
    // source quad qs = (l&3) ^ ((rl>>1)&3). Row offsets that are multiples of
    // 16 leave the key unchanged.
    const int rl = l >> 2;                         // 0..15
    const int qs = (l & 3) ^ ((rl >> 1) & 3);
    // x: wave wv stages rows 64wv .. 64wv+63 (4 instrs, +0/16/32/48)
    const float* xg0 = x + (size_t)(bt0 + 64 * wv + rl) * INF + qs * 4;
    // W: wave wv stages rows 32wv .. 32wv+31 (2 instrs, +0/16)
    const float* wg0 = W + (size_t)(h0 + 32 * wv + rl) * INF + qs * 4;
    const int xOff = (64 * wv) * KCH;              // wave-uniform float offset
    const int wOff = (32 * wv) * KCH;

    // ---- prologue: stage chunk 0 into buffer 0 ----
    GLD16(xg0,            xs + xOff);
    GLD16(xg0 + 16 * INF, xs + xOff + 256);
    GLD16(xg0 + 32 * INF, xs + xOff + 512);
    GLD16(xg0 + 48 * INF, xs + xOff + 768);
    GLD16(wg0,            ws + wOff);
    GLD16(wg0 + 16 * INF, ws + wOff + 256);

    float acc[16][8];
    #pragma unroll
    for (int r = 0; r < 16; ++r)
        #pragma unroll
        for (int c = 0; c < 8; ++c) acc[r][c] = 0.0f;

    const int keyx = (ly >> 1) & 3;   // lane-constant quad XOR keys
    const int keyw = (lx >> 1) & 3;

    __syncthreads();   // drains vmcnt -> chunk 0 resident

    for (int kc = 0; kc < NCH; ++kc) {
        const int p  = kc & 1;
        const int np = p ^ 1;

        // ---- issue next chunk's DMAs into the other buffer (async) ----
        if (kc + 1 < NCH) {
            const int so = (kc + 1) * KCH;         // float offset within a row
            float* xd = xs + np * XTILEF;
            float* wd = ws + np * WTILEF;
            GLD16(xg0 + so,            xd + xOff);
            GLD16(xg0 + so + 16 * INF, xd + xOff + 256);
            GLD16(xg0 + so + 32 * INF, xd + xOff + 512);
            GLD16(xg0 + so + 48 * INF, xd + xOff + 768);
            GLD16(wg0 + so,            wd + wOff);
            GLD16(wg0 + so + 16 * INF, wd + wOff + 256);
        }

        // ---- compute on current buffer: 4 groups of 4 k, g ascending ----
        const float* xrow = xs + p * XTILEF + (wbt + ly) * KCH;
        const float* wrow = ws + p * WTILEF + (wh  + lx) * KCH;
        #pragma unroll
        for (int g = 0; g < 4; ++g) {
            const float* xg_ = xrow + (g ^ keyx) * 4;
            const float* wg_ = wrow + (g ^ keyw) * 4;
            float4 wf[8];
            #pragma unroll
            for (int c = 0; c < 8; ++c)
                wf[c] = *(const float4*)(wg_ + c * 8 * KCH);
            #pragma unroll
            for (int r = 0; r < 16; ++r) {
                float4 xf = *(const float4*)(xg_ + r * 8 * KCH);
                // per-output order: g ascending, then components ascending
                #pragma unroll
                for (int c = 0; c < 8; ++c)
                    acc[r][c] = __fmaf_rn(xf.x, wf[c].x, acc[r][c]);
                #pragma unroll
                for (int c = 0; c < 8; ++c)
                    acc[r][c] = __fmaf_rn(xf.y, wf[c].y, acc[r][c]);
                #pragma unroll
                for (int c = 0; c < 8; ++c)
                    acc[r][c] = __fmaf_rn(xf.z, wf[c].z, acc[r][c]);
                #pragma unroll
                for (int c = 0; c < 8; ++c)
                    acc[r][c] = __fmaf_rn(xf.w, wf[c].w, acc[r][c]);
            }
        }
        __syncthreads();   // all waves done with buf p; buf np's DMAs drained
    }

    // ---- epilogue: one fp32 rounding for bias ----
    float bv[8];
    #pragma unroll
    for (int c = 0; c < 8; ++c) bv[c] = bias[h0 + wh + lx + 8 * c];
    #pragma unroll
    for (int r = 0; r < 16; ++r) {
        float* orow = hidden + (size_t)(bt0 + wbt + ly + 8 * r) * HIDF
                             + h0 + wh + lx;
        #pragma unroll
        for (int c = 0; c < 8; ++c)
            orow[8 * c] = __fadd_rn(acc[r][c], bv[c]);
    }
}

// ---------------------------------------------------------------------------
// Phase 2: in-place LIF scan over t, fp32:
//   mem = fl32(0.5*mem + h_t); spk = mem > 1.0f; hard reset to 0.
// Thread owns 2 adjacent h (float2 vector loads/stores), bursts of 32 t.
// 16384 threads = 256 blocks x 64 -> 1 wave/CU; small fixed arrays (no spill).
// ---------------------------------------------------------------------------
__global__ __launch_bounds__(64)
void snn_scan_np(float* __restrict__ io) {
    const int n  = blockIdx.x * 64 + threadIdx.x;   // 0..16383
    const int b  = n >> 9;
    const int h2 = n & 511;                          // float2 column
    float2* p = (float2*)io + (size_t)b * TIME * 512 + h2;

    float m0 = 0.0f, m1 = 0.0f;
    for (int tb = 0; tb < TIME / 32; ++tb) {
        float2 v[32];
        #pragma unroll
        for (int u = 0; u < 32; ++u) v[u] = p[(size_t)(tb * 32 + u) * 512];
        #pragma unroll
        for (int u = 0; u < 32; ++u) {
            m0 = __fadd_rn(__fmul_rn(0.5f, m0), v[u].x);
            m1 = __fadd_rn(__fmul_rn(0.5f, m1), v[u].y);
            bool s0 = m0 > 1.0f, s1 = m1 > 1.0f;
            v[u].x = s0 ? 1.0f : 0.0f;
            v[u].y = s1 ? 1.0f : 0.0f;
            if (s0) m0 = 0.0f;
            if (s1) m1 = 0.0f;
        }
        #pragma unroll
        for (int u = 0; u < 32; ++u) p[(size_t)(tb * 32 + u) * 512] = v[u];
    }
}

extern "C" void kernel_launch(void* const* d_in, const int* in_sizes, int n_in,
                              void* d_out, int out_size, void* d_ws, size_t ws_size,
                              hipStream_t stream) {
    const float* x    = (const float*)d_in[0];   // [32, 512, 512]
    const float* W    = (const float*)d_in[1];   // [1024, 512]
    const float* bias = (const float*)d_in[2];   // [1024]
    float* out = (float*)d_out;                  // [32, 512, 1024]

    dim3 g1(HIDF / NBH, (BATCH * TIME) / MBT);   // (8, 64) = 512 blocks
    snn_gemm_seqfma<<<g1, 256, 0, stream>>>(x, W, bias, out);

    snn_scan_np<<<(BATCH * HIDF / 2) / 64, 64, 0, stream>>>(out);
}